// Round 6
// baseline (261.852 us; speedup 1.0000x reference)
//
#include <hip/hip_runtime.h>
#include <hip/hip_bf16.h>

#define D_MODEL 1024
#define N3      3072
#define TSEQ    2048
#define M_TOT   8192

typedef __bf16 bf16_8 __attribute__((ext_vector_type(8)));
typedef float  f32x4  __attribute__((ext_vector_type(4)));
typedef short  s16x4  __attribute__((ext_vector_type(4)));

static __device__ __forceinline__ unsigned short f2bf(float f) {
  __hip_bfloat16 h = __float2bfloat16(f);
  unsigned short u;
  __builtin_memcpy(&u, &h, 2);
  return u;
}
static __device__ __forceinline__ unsigned pack2(float lo, float hi) {
  return (unsigned)f2bf(lo) | ((unsigned)f2bf(hi) << 16);
}
static __device__ __forceinline__ void gload16(const void* g, void* l) {
  __builtin_amdgcn_global_load_lds((const __attribute__((address_space(1))) void*)g,
                                   (__attribute__((address_space(3))) void*)l, 16, 0, 0);
}

// ---------------- convert x: fp32 -> bf16 ----------------
__global__ void cvt_x_kernel(const float* __restrict__ x, __bf16* __restrict__ xb) {
  size_t i = (size_t)blockIdx.x * 256 + threadIdx.x;   // each thread: 4 floats
  float4 v = *(const float4*)(x + i * 4);
  ushort4 o;
  o.x = f2bf(v.x); o.y = f2bf(v.y); o.z = f2bf(v.z); o.w = f2bf(v.w);
  *(ushort4*)((unsigned short*)xb + i * 4) = o;
}

// ------------- convert+transpose W: [1024][3072] f32 -> WT [3072][1024] bf16 -------------
__global__ void cvt_w_kernel(const float* __restrict__ W, __bf16* __restrict__ WT) {
  __shared__ unsigned short tl[64][68];
  int t = threadIdx.x;
  int n0 = blockIdx.x * 64, k0 = blockIdx.y * 64;
  int rr = t >> 4, cc = (t & 15) * 4;
#pragma unroll
  for (int i = 0; i < 4; ++i) {
    int r = rr + i * 16;                       // k-local
    float4 v = *(const float4*)(W + (size_t)(k0 + r) * N3 + n0 + cc);
    tl[r][cc] = f2bf(v.x); tl[r][cc + 1] = f2bf(v.y);
    tl[r][cc + 2] = f2bf(v.z); tl[r][cc + 3] = f2bf(v.w);
  }
  __syncthreads();
#pragma unroll
  for (int i = 0; i < 4; ++i) {
    int rc = rr + i * 16;                      // n-local
    ushort4 o;
    o.x = tl[cc + 0][rc]; o.y = tl[cc + 1][rc];
    o.z = tl[cc + 2][rc]; o.w = tl[cc + 3][rc];
    *(ushort4*)((unsigned short*)WT + (size_t)(n0 + rc) * D_MODEL + k0 + cc) = o;
  }
}

// ------------- transpose V-part of qkv -> VT [bh][c=64][t=2048] bf16 -------------
__global__ void vtrans_kernel(const __bf16* __restrict__ qkv, __bf16* __restrict__ VT) {
  __shared__ unsigned short tl[64][68];
  int t = threadIdx.x;
  int t0 = blockIdx.x * 64;
  int bh = blockIdx.y;
  int b = bh >> 4, h = bh & 15;
  int rr = t >> 4, cc = (t & 15) * 4;
  const unsigned short* q16 = (const unsigned short*)qkv;
#pragma unroll
  for (int i = 0; i < 4; ++i) {
    int r = rr + i * 16;                       // t-local
    ushort4 v = *(const ushort4*)(q16 + (size_t)(b * TSEQ + t0 + r) * N3 + 2048 + h * 64 + cc);
    tl[r][cc] = v.x; tl[r][cc + 1] = v.y; tl[r][cc + 2] = v.z; tl[r][cc + 3] = v.w;
  }
  __syncthreads();
#pragma unroll
  for (int i = 0; i < 4; ++i) {
    int rc = rr + i * 16;                      // c-local
    ushort4 o;
    o.x = tl[cc + 0][rc]; o.y = tl[cc + 1][rc];
    o.z = tl[cc + 2][rc]; o.w = tl[cc + 3][rc];
    *(ushort4*)((unsigned short*)VT + (size_t)(bh * 64 + rc) * TSEQ + t0 + cc) = o;
  }
}

// ------------- GEMM: qkv = xb[8192][1024] @ WT[3072][1024]^T + bias, bf16 out -------------
__global__ __launch_bounds__(256, 2) void gemm_qkv_kernel(
    const __bf16* __restrict__ A, const __bf16* __restrict__ Bt,
    const float* __restrict__ bias, __bf16* __restrict__ C) {
  __shared__ __align__(16) __bf16 Al[2][4096];
  __shared__ __align__(16) __bf16 Bl[2][4096];
  int tid = threadIdx.x;
  int wave = tid >> 6, lane = tid & 63;
  int lr = lane & 15, lg = lane >> 4;
  int m0 = blockIdx.x * 128, n0 = blockIdx.y * 128;
  int wm = (wave >> 1) * 64, wn = (wave & 1) * 64;

  const f32x4 fz = {0.f, 0.f, 0.f, 0.f};
  f32x4 acc[4][4];
#pragma unroll
  for (int i = 0; i < 4; ++i)
#pragma unroll
    for (int j = 0; j < 4; ++j) acc[i][j] = fz;

  auto stage = [&](int buf, int kt) {
#pragma unroll
    for (int call = 0; call < 2; ++call) {
      int cb = call * 256 + wave * 64;         // wave-uniform LDS chunk base
      int c = cb + lane;
      int row = c >> 2;
      int cir = (c & 3) ^ ((row >> 1) & 3);    // XOR swizzle (source side)
      gload16(A + (size_t)(m0 + row) * D_MODEL + kt * 32 + cir * 8, &Al[buf][cb * 8]);
      gload16(Bt + (size_t)(n0 + row) * D_MODEL + kt * 32 + cir * 8, &Bl[buf][cb * 8]);
    }
  };

  stage(0, 0);
  __syncthreads();
  for (int kt = 0; kt < 32; ++kt) {
    int buf = kt & 1;
    if (kt + 1 < 32) stage(buf ^ 1, kt + 1);
    bf16_8 af[4], bv[4];
#pragma unroll
    for (int mb = 0; mb < 4; ++mb) {
      int row = wm + mb * 16 + lr;
      int cir = lg ^ ((row >> 1) & 3);         // XOR swizzle (read side)
      af[mb] = *(const bf16_8*)&Al[buf][row * 32 + cir * 8];
    }
#pragma unroll
    for (int nb = 0; nb < 4; ++nb) {
      int row = wn + nb * 16 + lr;
      int cir = lg ^ ((row >> 1) & 3);
      bv[nb] = *(const bf16_8*)&Bl[buf][row * 32 + cir * 8];
    }
#pragma unroll
    for (int mb = 0; mb < 4; ++mb)
#pragma unroll
      for (int nb = 0; nb < 4; ++nb)
        acc[mb][nb] = __builtin_amdgcn_mfma_f32_16x16x32_bf16(af[mb], bv[nb], acc[mb][nb], 0, 0, 0);
    __syncthreads();
  }

  float bvs[4];
#pragma unroll
  for (int nb = 0; nb < 4; ++nb) bvs[nb] = bias[n0 + wn + nb * 16 + lr];
  unsigned short* C16 = (unsigned short*)C;
#pragma unroll
  for (int mb = 0; mb < 4; ++mb)
#pragma unroll
    for (int nb = 0; nb < 4; ++nb)
#pragma unroll
      for (int r = 0; r < 4; ++r) {
        int row = m0 + wm + mb * 16 + lg * 4 + r;
        int col = n0 + wn + nb * 16 + lr;
        C16[(size_t)row * N3 + col] = f2bf(acc[mb][nb][r] + bvs[nb]);
      }
}

// ------------- fused causal attention: direct-from-L2, zero LDS, zero barriers -------------
// Each wave owns 32 q-rows; pass-paired (rows 32p, then 2016-32p) for balance.
// XCD swizzle: all blocks of a given (b,h) land on one XCD -> K/V L2-resident.
__global__ __launch_bounds__(128, 2) void attn_kernel(
    const __bf16* __restrict__ qkv, const __bf16* __restrict__ VT,
    float* __restrict__ out) {
  int bx = blockIdx.x, byy = blockIdx.y;       // grid (16, 64)
  int bh = (bx & 7) + 8 * (byy & 7);           // XCD = linear%8 = bx&7 -> same bh same XCD
  int wave = threadIdx.x >> 6;
  int job = ((bx >> 3) + 2 * (byy >> 3)) * 2 + wave;   // 0..31
  int b = bh >> 4, h = bh & 15;
  int lane = threadIdx.x & 63;
  int lr = lane & 15, lg = lane >> 4;

  const __bf16* Kg = qkv + (size_t)b * TSEQ * N3 + 1024 + h * 64;  // + t*N3
  const __bf16* Vg = VT + (size_t)bh * 64 * TSEQ;                  // + c*TSEQ
  const float SC = 0.04508422f;                // log2(e)/32  (scale 1/sqrt(1024))

  for (int pass = 0; pass < 2; ++pass) {
    int q0 = pass ? (2016 - 32 * job) : (32 * job);

    // Q as B-fragments: B[k=c][n=q] = Q[q][c]
    bf16_8 qf[2][2];
#pragma unroll
    for (int nb = 0; nb < 2; ++nb)
#pragma unroll
      for (int kk = 0; kk < 2; ++kk) {
        int tq = q0 + nb * 16 + lr;
        qf[nb][kk] = *(const bf16_8*)&qkv[(size_t)(b * TSEQ + tq) * N3 + h * 64 + kk * 32 + lg * 8];
      }

    float mreg[2] = {-1e30f, -1e30f};
    float lreg[2] = {0.f, 0.f};
    const f32x4 fz = {0.f, 0.f, 0.f, 0.f};
    f32x4 oacc[4][2];
#pragma unroll
    for (int i = 0; i < 4; ++i) { oacc[i][0] = fz; oacc[i][1] = fz; }

    int ntw = (q0 + 95) >> 6;                  // tiles needed to cover q0+31
    for (int tt = 0; tt < ntw; ++tt) {
      int kv0 = tt * 64;
      // K fragments direct from global (L2-hot): A[m=kv][k=c]
      bf16_8 kf[2][4];
#pragma unroll
      for (int kk = 0; kk < 2; ++kk)
#pragma unroll
        for (int mb = 0; mb < 4; ++mb)
          kf[kk][mb] = *(const bf16_8*)(Kg + (size_t)(kv0 + mb * 16 + lr) * N3 + kk * 32 + lg * 8);
      // S^T[kv][q] = K · Q^T
      f32x4 st[4][2];
#pragma unroll
      for (int i = 0; i < 4; ++i) { st[i][0] = fz; st[i][1] = fz; }
      __builtin_amdgcn_s_setprio(1);
#pragma unroll
      for (int kk = 0; kk < 2; ++kk)
#pragma unroll
        for (int mb = 0; mb < 4; ++mb)
#pragma unroll
          for (int nb = 0; nb < 2; ++nb)
            st[mb][nb] = __builtin_amdgcn_mfma_f32_16x16x32_bf16(kf[kk][mb], qf[nb][kk], st[mb][nb], 0, 0, 0);
      __builtin_amdgcn_s_setprio(0);
      // mask + scale into log2 domain (uniform branch)
      float sv[4][2][4];
      if (kv0 + 63 > q0) {
#pragma unroll
        for (int mb = 0; mb < 4; ++mb)
#pragma unroll
          for (int nb = 0; nb < 2; ++nb)
#pragma unroll
            for (int r = 0; r < 4; ++r) {
              float s = st[mb][nb][r] * SC;
              int kv = kv0 + mb * 16 + lg * 4 + r;
              int qq = q0 + nb * 16 + lr;
              sv[mb][nb][r] = (kv > qq) ? -1e30f : s;
            }
      } else {
#pragma unroll
        for (int mb = 0; mb < 4; ++mb)
#pragma unroll
          for (int nb = 0; nb < 2; ++nb)
#pragma unroll
            for (int r = 0; r < 4; ++r)
              sv[mb][nb][r] = st[mb][nb][r] * SC;
      }
      // online softmax (per q-column state; column = lr), defer-max THR=8
      float tm[2];
#pragma unroll
      for (int nb = 0; nb < 2; ++nb) {
        float a0 = fmaxf(fmaxf(sv[0][nb][0], sv[0][nb][1]), fmaxf(sv[0][nb][2], sv[0][nb][3]));
        float a1 = fmaxf(fmaxf(sv[1][nb][0], sv[1][nb][1]), fmaxf(sv[1][nb][2], sv[1][nb][3]));
        float a2 = fmaxf(fmaxf(sv[2][nb][0], sv[2][nb][1]), fmaxf(sv[2][nb][2], sv[2][nb][3]));
        float a3 = fmaxf(fmaxf(sv[3][nb][0], sv[3][nb][1]), fmaxf(sv[3][nb][2], sv[3][nb][3]));
        float t = fmaxf(fmaxf(a0, a1), fmaxf(a2, a3));
        t = fmaxf(t, __shfl_xor(t, 16, 64));
        t = fmaxf(t, __shfl_xor(t, 32, 64));
        tm[nb] = t;
      }
      if (!(__all(tm[0] <= mreg[0] + 8.f) && __all(tm[1] <= mreg[1] + 8.f))) {
#pragma unroll
        for (int nb = 0; nb < 2; ++nb) {
          float mn = fmaxf(mreg[nb], tm[nb]);
          float fac = __builtin_amdgcn_exp2f(mreg[nb] - mn);
          mreg[nb] = mn;
          lreg[nb] *= fac;
#pragma unroll
          for (int mbc = 0; mbc < 4; ++mbc) oacc[mbc][nb] *= fac;
        }
      }
      float ps[2] = {0.f, 0.f};
      unsigned pw[4][2][2];
#pragma unroll
      for (int mb = 0; mb < 4; ++mb)
#pragma unroll
        for (int nb = 0; nb < 2; ++nb) {
          float p0 = __builtin_amdgcn_exp2f(sv[mb][nb][0] - mreg[nb]);
          float p1 = __builtin_amdgcn_exp2f(sv[mb][nb][1] - mreg[nb]);
          float p2 = __builtin_amdgcn_exp2f(sv[mb][nb][2] - mreg[nb]);
          float p3 = __builtin_amdgcn_exp2f(sv[mb][nb][3] - mreg[nb]);
          ps[nb] += (p0 + p1) + (p2 + p3);
          pw[mb][nb][0] = pack2(p0, p1);
          pw[mb][nb][1] = pack2(p2, p3);
        }
#pragma unroll
      for (int nb = 0; nb < 2; ++nb) {
        float s = ps[nb];
        s += __shfl_xor(s, 16, 64);
        s += __shfl_xor(s, 32, 64);
        lreg[nb] += s;
      }
      // PV: O^T[c][q] += V^T · P^T (16x16x16; pw pairs are the B-fragment directly).
      // V^T A-frag direct from VT: lane (lr,lg) elem k = lg*4+j, m = c = mbc*16+lr.
#pragma unroll
      for (int mb = 0; mb < 4; ++mb) {
        s16x4 vf[4];
#pragma unroll
        for (int mbc = 0; mbc < 4; ++mbc)
          vf[mbc] = *(const s16x4*)(Vg + (size_t)(mbc * 16 + lr) * TSEQ + kv0 + mb * 16 + lg * 4);
        __builtin_amdgcn_s_setprio(1);
#pragma unroll
        for (int nb = 0; nb < 2; ++nb) {
          union { unsigned u[2]; s16x4 v; } pf;
          pf.u[0] = pw[mb][nb][0];
          pf.u[1] = pw[mb][nb][1];
#pragma unroll
          for (int mbc = 0; mbc < 4; ++mbc)
            oacc[mbc][nb] = __builtin_amdgcn_mfma_f32_16x16x16bf16_1k(vf[mbc], pf.v, oacc[mbc][nb], 0, 0, 0);
        }
        __builtin_amdgcn_s_setprio(0);
      }
    }

    // epilogue: direct global scalar stores (L2 write-back merges lines)
    float invl[2] = {1.f / lreg[0], 1.f / lreg[1]};
#pragma unroll
    for (int mbc = 0; mbc < 4; ++mbc)
#pragma unroll
      for (int nb = 0; nb < 2; ++nb)
#pragma unroll
        for (int r = 0; r < 4; ++r) {
          int q = q0 + nb * 16 + lr;
          int c = mbc * 16 + lg * 4 + r;
          out[(size_t)(b * TSEQ + q) * D_MODEL + h * 64 + c] = oacc[mbc][nb][r] * invl[nb];
        }
  }
}

extern "C" void kernel_launch(void* const* d_in, const int* in_sizes, int n_in,
                              void* d_out, int out_size, void* d_ws, size_t ws_size,
                              hipStream_t stream) {
  const float* x = (const float*)d_in[0];
  const float* W = (const float*)d_in[1];
  const float* bias = (const float*)d_in[2];
  float* out = (float*)d_out;
  char* ws = (char*)d_ws;
  __bf16* xb  = (__bf16*)(ws);                        // 16,777,216 B
  __bf16* WT  = (__bf16*)(ws + (size_t)16777216);     //  6,291,456 B
  __bf16* qkv = (__bf16*)(ws + (size_t)23068672);     // 50,331,648 B
  __bf16* VT  = (__bf16*)(ws + (size_t)73400320);     // 16,777,216 B  (total ~90 MB)

  hipLaunchKernelGGL(cvt_x_kernel, dim3(8192), dim3(256), 0, stream, x, xb);
  hipLaunchKernelGGL(cvt_w_kernel, dim3(48, 16), dim3(256), 0, stream, W, WT);
  hipLaunchKernelGGL(gemm_qkv_kernel, dim3(64, 24), dim3(256), 0, stream, xb, WT, bias, qkv);
  hipLaunchKernelGGL(vtrans_kernel, dim3(32, 64), dim3(256), 0, stream, qkv, VT);
  hipLaunchKernelGGL(attn_kernel, dim3(16, 64), dim3(128), 0, stream, qkv, VT, out);
}

// Round 7
// 175.957 us; speedup vs baseline: 1.4882x; 1.4882x over previous
//
#include <hip/hip_runtime.h>
#include <hip/hip_bf16.h>

#define D_MODEL 1024
#define N3      3072
#define TSEQ    2048
#define M_TOT   8192
#define BKG     64

typedef __bf16 bf16_8 __attribute__((ext_vector_type(8)));
typedef float  f32x4  __attribute__((ext_vector_type(4)));
typedef short  s16x4  __attribute__((ext_vector_type(4)));

static __device__ __forceinline__ unsigned short f2bf(float f) {
  __hip_bfloat16 h = __float2bfloat16(f);
  unsigned short u;
  __builtin_memcpy(&u, &h, 2);
  return u;
}
static __device__ __forceinline__ unsigned pack2(float lo, float hi) {
  return (unsigned)f2bf(lo) | ((unsigned)f2bf(hi) << 16);
}
static __device__ __forceinline__ void gload16(const void* g, void* l) {
  __builtin_amdgcn_global_load_lds((const __attribute__((address_space(1))) void*)g,
                                   (__attribute__((address_space(3))) void*)l, 16, 0, 0);
}

// ---------------- convert x: fp32 -> bf16 ----------------
__global__ void cvt_x_kernel(const float* __restrict__ x, __bf16* __restrict__ xb) {
  size_t i = (size_t)blockIdx.x * 256 + threadIdx.x;   // each thread: 4 floats
  float4 v = *(const float4*)(x + i * 4);
  ushort4 o;
  o.x = f2bf(v.x); o.y = f2bf(v.y); o.z = f2bf(v.z); o.w = f2bf(v.w);
  *(ushort4*)((unsigned short*)xb + i * 4) = o;
}

// ------------- convert+transpose W: [1024][3072] f32 -> WT [3072][1024] bf16 -------------
__global__ void cvt_w_kernel(const float* __restrict__ W, __bf16* __restrict__ WT) {
  __shared__ unsigned short tl[64][68];
  int t = threadIdx.x;
  int n0 = blockIdx.x * 64, k0 = blockIdx.y * 64;
  int rr = t >> 4, cc = (t & 15) * 4;
#pragma unroll
  for (int i = 0; i < 4; ++i) {
    int r = rr + i * 16;                       // k-local
    float4 v = *(const float4*)(W + (size_t)(k0 + r) * N3 + n0 + cc);
    tl[r][cc] = f2bf(v.x); tl[r][cc + 1] = f2bf(v.y);
    tl[r][cc + 2] = f2bf(v.z); tl[r][cc + 3] = f2bf(v.w);
  }
  __syncthreads();
#pragma unroll
  for (int i = 0; i < 4; ++i) {
    int rc = rr + i * 16;                      // n-local
    ushort4 o;
    o.x = tl[cc + 0][rc]; o.y = tl[cc + 1][rc];
    o.z = tl[cc + 2][rc]; o.w = tl[cc + 3][rc];
    *(ushort4*)((unsigned short*)WT + (size_t)(n0 + rc) * D_MODEL + k0 + cc) = o;
  }
}

// ------------- transpose V-part of qkv -> VT [bh][c=64][t=2048] bf16 -------------
__global__ void vtrans_kernel(const __bf16* __restrict__ qkv, __bf16* __restrict__ VT) {
  __shared__ unsigned short tl[64][68];
  int t = threadIdx.x;
  int t0 = blockIdx.x * 64;
  int bh = blockIdx.y;
  int b = bh >> 4, h = bh & 15;
  int rr = t >> 4, cc = (t & 15) * 4;
  const unsigned short* q16 = (const unsigned short*)qkv;
#pragma unroll
  for (int i = 0; i < 4; ++i) {
    int r = rr + i * 16;                       // t-local
    ushort4 v = *(const ushort4*)(q16 + (size_t)(b * TSEQ + t0 + r) * N3 + 2048 + h * 64 + cc);
    tl[r][cc] = v.x; tl[r][cc + 1] = v.y; tl[r][cc + 2] = v.z; tl[r][cc + 3] = v.w;
  }
  __syncthreads();
#pragma unroll
  for (int i = 0; i < 4; ++i) {
    int rc = rr + i * 16;                      // c-local
    ushort4 o;
    o.x = tl[cc + 0][rc]; o.y = tl[cc + 1][rc];
    o.z = tl[cc + 2][rc]; o.w = tl[cc + 3][rc];
    *(ushort4*)((unsigned short*)VT + (size_t)(bh * 64 + rc) * TSEQ + t0 + cc) = o;
  }
}

// ------------- GEMM: qkv = xb[8192][1024] @ WT[3072][1024]^T + bias, bf16 out -------------
// BK=64, counted-vmcnt pipeline: steady-state wait is vmcnt(4), never 0.
__global__ __launch_bounds__(256, 2) void gemm_qkv_kernel(
    const __bf16* __restrict__ A, const __bf16* __restrict__ Bt,
    const float* __restrict__ bias, __bf16* __restrict__ C) {
  __shared__ __align__(16) __bf16 Al[2][128 * BKG];
  __shared__ __align__(16) __bf16 Bl[2][128 * BKG];
  int tid = threadIdx.x;
  int wave = tid >> 6, lane = tid & 63;
  int lr = lane & 15, lg = lane >> 4;
  // XCD swizzle: 1536 blocks = 8 XCDs x 192; each XCD owns 3 contiguous n-panels.
  int lin = blockIdx.y * 64 + blockIdx.x;      // grid (64, 24)
  int rid = (lin & 7) * 192 + (lin >> 3);
  int m0 = (rid & 63) * 128, n0 = (rid >> 6) * 128;
  int wm = (wave >> 1) * 64, wn = (wave & 1) * 64;

  const f32x4 fz = {0.f, 0.f, 0.f, 0.f};
  f32x4 acc[4][4];
#pragma unroll
  for (int i = 0; i < 4; ++i)
#pragma unroll
    for (int j = 0; j < 4; ++j) acc[i][j] = fz;

  // half = 2 A-chunk loads + 2 B-chunk loads per thread (4 VMEM instrs)
  auto stage = [&](int buf, int kt, int half) {
#pragma unroll
    for (int i = half * 2; i < half * 2 + 2; ++i) {
      int cb = i * 256 + wave * 64;            // wave-uniform chunk base
      int c = cb + lane;
      int row = c >> 3;                        // 0..127
      int lc = (c & 7) ^ (row & 7);            // source-side XOR swizzle (16B granule)
      gload16(A + (size_t)(m0 + row) * D_MODEL + kt * BKG + lc * 8, (char*)&Al[buf][0] + cb * 16);
      gload16(Bt + (size_t)(n0 + row) * D_MODEL + kt * BKG + lc * 8, (char*)&Bl[buf][0] + cb * 16);
    }
  };

  const int NT = D_MODEL / BKG;                // 16
  stage(0, 0, 0); stage(0, 0, 1);              // L_0 (8 loads)
  stage(1, 1, 0);                              // L_1 half0 (4 loads)
  asm volatile("s_waitcnt vmcnt(4)" ::: "memory");   // L_0 done, L_1h0 in flight
  __builtin_amdgcn_sched_barrier(0);
  __builtin_amdgcn_s_barrier();

  for (int t = 0; t < NT; ++t) {
    int cbuf = t & 1;
    if (t + 1 < NT) stage(cbuf ^ 1, t + 1, 1); // L_{t+1} half1
    bf16_8 af[4][2], bv[4][2];
#pragma unroll
    for (int mb = 0; mb < 4; ++mb)
#pragma unroll
      for (int kk = 0; kk < 2; ++kk) {
        int row = wm + mb * 16 + lr;
        int pc = (kk * 4 + lg) ^ (row & 7);    // read-side swizzle
        af[mb][kk] = *(const bf16_8*)&Al[cbuf][row * BKG + pc * 8];
      }
#pragma unroll
    for (int nb = 0; nb < 4; ++nb)
#pragma unroll
      for (int kk = 0; kk < 2; ++kk) {
        int row = wn + nb * 16 + lr;
        int pc = (kk * 4 + lg) ^ (row & 7);
        bv[nb][kk] = *(const bf16_8*)&Bl[cbuf][row * BKG + pc * 8];
      }
    __builtin_amdgcn_s_setprio(1);
#pragma unroll
    for (int kk = 0; kk < 2; ++kk)
#pragma unroll
      for (int mb = 0; mb < 4; ++mb)
#pragma unroll
        for (int nb = 0; nb < 4; ++nb)
          acc[mb][nb] = __builtin_amdgcn_mfma_f32_16x16x32_bf16(af[mb][kk], bv[nb][kk], acc[mb][nb], 0, 0, 0);
    __builtin_amdgcn_s_setprio(0);
    asm volatile("s_waitcnt lgkmcnt(0)" ::: "memory");
    __builtin_amdgcn_sched_barrier(0);
    __builtin_amdgcn_s_barrier();              // all waves done reading buf cbuf
    if (t + 2 < NT) {
      stage(cbuf, t + 2, 0);                   // L_{t+2} half0 into just-freed buf
      asm volatile("s_waitcnt vmcnt(4)" ::: "memory");   // L_{t+1} fully landed
    } else if (t + 1 < NT) {
      asm volatile("s_waitcnt vmcnt(0)" ::: "memory");
    }
    __builtin_amdgcn_sched_barrier(0);
    if (t + 1 < NT) __builtin_amdgcn_s_barrier();
  }

  float bvs[4];
#pragma unroll
  for (int nb = 0; nb < 4; ++nb) bvs[nb] = bias[n0 + wn + nb * 16 + lr];
  unsigned short* C16 = (unsigned short*)C;
#pragma unroll
  for (int mb = 0; mb < 4; ++mb)
#pragma unroll
    for (int nb = 0; nb < 4; ++nb)
#pragma unroll
      for (int r = 0; r < 4; ++r) {
        int row = m0 + wm + mb * 16 + lg * 4 + r;
        int col = n0 + wn + nb * 16 + lr;
        C16[(size_t)row * N3 + col] = f2bf(acc[mb][nb][r] + bvs[nb]);
      }
}

// ------------- fused causal attention (flash-style, swapped QK^T) -------------
// Work-balanced: block bx processes q-tiles (15-bx) then (bx): 34 kv-tile units each.
// PV uses 16x16x16 MFMA: packed P words ARE the B-fragment (no cross-lane relayout).
__global__ __launch_bounds__(256, 2) void attn_kernel(
    const __bf16* __restrict__ qkv, const __bf16* __restrict__ VT,
    float* __restrict__ out) {
  __shared__ __align__(16) char smem[35840];
  __bf16* Kl = (__bf16*)smem;                  // [2][4096]
  __bf16* Vl = (__bf16*)(smem + 16384);        // [2][4096]

  int bx = blockIdx.x, bh = blockIdx.y;
  int b = bh >> 4, h = bh & 15;
  int tid = threadIdx.x, wave = tid >> 6, lane = tid & 63;
  int lr = lane & 15, lg = lane >> 4;

  const __bf16* Kg = qkv + (size_t)b * TSEQ * N3 + 1024 + h * 64;  // + t*N3
  const __bf16* Vg = VT + (size_t)bh * 64 * TSEQ;                  // + c*TSEQ
  const float SC = 0.04508422f;                // log2(e)/32  (scale 1/sqrt(1024))

  auto stage = [&](int buf, int kv0) {
#pragma unroll
    for (int call = 0; call < 2; ++call) {
      int cb = call * 256 + wave * 64;
      int c = cb + lane;
      int row = c >> 3;
      int cir = (c & 7) ^ (row & 7);           // XOR swizzle (source side); row stride 128B
      gload16(Kg + (size_t)(kv0 + row) * N3 + cir * 8, Kl + buf * 4096 + cb * 8);
      gload16(Vg + (size_t)row * TSEQ + kv0 + cir * 8, Vl + buf * 4096 + cb * 8);
    }
  };

  for (int pass = 0; pass < 2; ++pass) {
    int qt = pass ? bx : (15 - bx);
    int q0 = qt * 128 + wave * 32;             // wave's q base

    // Q as B-fragments, straight from qkv: B[k=c][n=q] = Q[q][c]
    bf16_8 qf[2][2];
#pragma unroll
    for (int nb = 0; nb < 2; ++nb)
#pragma unroll
      for (int kk = 0; kk < 2; ++kk) {
        int tq = q0 + nb * 16 + lr;
        qf[nb][kk] = *(const bf16_8*)&qkv[(size_t)(b * TSEQ + tq) * N3 + h * 64 + kk * 32 + lg * 8];
      }

    float mreg[2] = {-1e30f, -1e30f};
    float lreg[2] = {0.f, 0.f};
    const f32x4 fz = {0.f, 0.f, 0.f, 0.f};
    f32x4 oacc[4][2];
#pragma unroll
    for (int i = 0; i < 4; ++i) { oacc[i][0] = fz; oacc[i][1] = fz; }

    int ntiles = (qt + 1) * 2;
    stage(0, 0);
    __syncthreads();
    for (int tt = 0; tt < ntiles; ++tt) {
      int buf = tt & 1;
      int kv0 = tt * 64;
      if (tt + 1 < ntiles) stage(buf ^ 1, (tt + 1) * 64);
      if (kv0 <= q0 + 31) {
        const __bf16* Kb = Kl + buf * 4096;
        const __bf16* Vb = Vl + buf * 4096;
        // S^T[kv][q] = K · Q^T
        f32x4 st[4][2];
#pragma unroll
        for (int i = 0; i < 4; ++i) { st[i][0] = fz; st[i][1] = fz; }
#pragma unroll
        for (int kk = 0; kk < 2; ++kk) {
          bf16_8 kf[4];
#pragma unroll
          for (int mb = 0; mb < 4; ++mb) {
            int row = mb * 16 + lr;
            int cir = (kk * 4 + lg) ^ (row & 7); // XOR swizzle (read side)
            kf[mb] = *(const bf16_8*)&Kb[row * 64 + cir * 8];
          }
          __builtin_amdgcn_s_setprio(1);
#pragma unroll
          for (int mb = 0; mb < 4; ++mb)
#pragma unroll
            for (int nb = 0; nb < 2; ++nb)
              st[mb][nb] = __builtin_amdgcn_mfma_f32_16x16x32_bf16(kf[mb], qf[nb][kk], st[mb][nb], 0, 0, 0);
          __builtin_amdgcn_s_setprio(0);
        }
        // mask + scale into log2 domain (uniform branch: non-diag tiles skip mask VALU)
        float sv[4][2][4];
        if (kv0 + 63 > q0) {
#pragma unroll
          for (int mb = 0; mb < 4; ++mb)
#pragma unroll
            for (int nb = 0; nb < 2; ++nb)
#pragma unroll
              for (int r = 0; r < 4; ++r) {
                float s = st[mb][nb][r] * SC;
                int kv = kv0 + mb * 16 + lg * 4 + r;
                int qq = q0 + nb * 16 + lr;
                sv[mb][nb][r] = (kv > qq) ? -1e30f : s;
              }
        } else {
#pragma unroll
          for (int mb = 0; mb < 4; ++mb)
#pragma unroll
            for (int nb = 0; nb < 2; ++nb)
#pragma unroll
              for (int r = 0; r < 4; ++r)
                sv[mb][nb][r] = st[mb][nb][r] * SC;
        }
        // online softmax (per q-column state; column = lr), defer-max THR=8
        float tm[2];
#pragma unroll
        for (int nb = 0; nb < 2; ++nb) {
          float a0 = fmaxf(fmaxf(sv[0][nb][0], sv[0][nb][1]), fmaxf(sv[0][nb][2], sv[0][nb][3]));
          float a1 = fmaxf(fmaxf(sv[1][nb][0], sv[1][nb][1]), fmaxf(sv[1][nb][2], sv[1][nb][3]));
          float a2 = fmaxf(fmaxf(sv[2][nb][0], sv[2][nb][1]), fmaxf(sv[2][nb][2], sv[2][nb][3]));
          float a3 = fmaxf(fmaxf(sv[3][nb][0], sv[3][nb][1]), fmaxf(sv[3][nb][2], sv[3][nb][3]));
          float t = fmaxf(fmaxf(a0, a1), fmaxf(a2, a3));
          t = fmaxf(t, __shfl_xor(t, 16, 64));
          t = fmaxf(t, __shfl_xor(t, 32, 64));
          tm[nb] = t;
        }
        if (!(__all(tm[0] <= mreg[0] + 8.f) && __all(tm[1] <= mreg[1] + 8.f))) {
#pragma unroll
          for (int nb = 0; nb < 2; ++nb) {
            float mn = fmaxf(mreg[nb], tm[nb]);
            float fac = __builtin_amdgcn_exp2f(mreg[nb] - mn);
            mreg[nb] = mn;
            lreg[nb] *= fac;
#pragma unroll
            for (int mbc = 0; mbc < 4; ++mbc) oacc[mbc][nb] *= fac;
          }
        }
        float ps[2] = {0.f, 0.f};
        unsigned pw[4][2][2];
#pragma unroll
        for (int mb = 0; mb < 4; ++mb)
#pragma unroll
          for (int nb = 0; nb < 2; ++nb) {
            float p0 = __builtin_amdgcn_exp2f(sv[mb][nb][0] - mreg[nb]);
            float p1 = __builtin_amdgcn_exp2f(sv[mb][nb][1] - mreg[nb]);
            float p2 = __builtin_amdgcn_exp2f(sv[mb][nb][2] - mreg[nb]);
            float p3 = __builtin_amdgcn_exp2f(sv[mb][nb][3] - mreg[nb]);
            ps[nb] += (p0 + p1) + (p2 + p3);
            pw[mb][nb][0] = pack2(p0, p1);
            pw[mb][nb][1] = pack2(p2, p3);
          }
#pragma unroll
        for (int nb = 0; nb < 2; ++nb) {
          float s = ps[nb];
          s += __shfl_xor(s, 16, 64);
          s += __shfl_xor(s, 32, 64);
          lreg[nb] += s;
        }
        // PV: O^T[c][q] += V^T · P^T  (16x16x16; pw pairs are the B-fragment directly)
#pragma unroll
        for (int mb = 0; mb < 4; ++mb) {
          s16x4 vf[4];
          int chunk = mb * 2 + (lg >> 1);      // 16B chunk of k-range mb*16 + lg*4
#pragma unroll
          for (int mbc = 0; mbc < 4; ++mbc) {
            int row = mbc * 16 + lr;
            int cir = chunk ^ (row & 7);       // same 16B-granule swizzle involution
            vf[mbc] = *(const s16x4*)((const char*)Vb + row * 128 + cir * 16 + (lg & 1) * 8);
          }
          __builtin_amdgcn_s_setprio(1);
#pragma unroll
          for (int nb = 0; nb < 2; ++nb) {
            union { unsigned u[2]; s16x4 v; } pf;
            pf.u[0] = pw[mb][nb][0];
            pf.u[1] = pw[mb][nb][1];
#pragma unroll
            for (int mbc = 0; mbc < 4; ++mbc)
              oacc[mbc][nb] = __builtin_amdgcn_mfma_f32_16x16x16bf16_1k(vf[mbc], pf.v, oacc[mbc][nb], 0, 0, 0);
          }
          __builtin_amdgcn_s_setprio(0);
        }
      }
      __syncthreads();
    }

    // epilogue: per-wave LDS transpose; stride 65 floats = bank-conflict-free
    float* Ow = (float*)smem + wave * (32 * 65);
    float invl[2] = {1.f / lreg[0], 1.f / lreg[1]};
#pragma unroll
    for (int mbc = 0; mbc < 4; ++mbc)
#pragma unroll
      for (int nb = 0; nb < 2; ++nb)
#pragma unroll
        for (int r = 0; r < 4; ++r)
          Ow[(nb * 16 + lr) * 65 + mbc * 16 + lg * 4 + r] = oacc[mbc][nb][r] * invl[nb];
    // same-wave readback: no barrier needed
    int qrow = lane >> 1, cs = (lane & 1) * 32;
    const float* srcp = Ow + qrow * 65 + cs;
    float* dst = out + (size_t)(b * TSEQ + q0 + qrow) * D_MODEL + h * 64 + cs;
#pragma unroll
    for (int j = 0; j < 8; ++j) {
      float4 v = *(const float4*)(srcp + j * 4);
      *(float4*)(dst + j * 4) = v;
    }
    __syncthreads();   // protect aliased epilogue scratch from next pass's staging
  }
}

extern "C" void kernel_launch(void* const* d_in, const int* in_sizes, int n_in,
                              void* d_out, int out_size, void* d_ws, size_t ws_size,
                              hipStream_t stream) {
  const float* x = (const float*)d_in[0];
  const float* W = (const float*)d_in[1];
  const float* bias = (const float*)d_in[2];
  float* out = (float*)d_out;
  char* ws = (char*)d_ws;
  __bf16* xb  = (__bf16*)(ws);                        // 16,777,216 B
  __bf16* WT  = (__bf16*)(ws + (size_t)16777216);     //  6,291,456 B
  __bf16* qkv = (__bf16*)(ws + (size_t)23068672);     // 50,331,648 B
  __bf16* VT  = (__bf16*)(ws + (size_t)73400320);     // 16,777,216 B  (total ~90 MB)

  hipLaunchKernelGGL(cvt_x_kernel, dim3(8192), dim3(256), 0, stream, x, xb);
  hipLaunchKernelGGL(cvt_w_kernel, dim3(48, 16), dim3(256), 0, stream, W, WT);
  hipLaunchKernelGGL(gemm_qkv_kernel, dim3(64, 24), dim3(256), 0, stream, xb, WT, bias, qkv);
  hipLaunchKernelGGL(vtrans_kernel, dim3(32, 64), dim3(256), 0, stream, qkv, VT);
  hipLaunchKernelGGL(attn_kernel, dim3(8, 64), dim3(256), 0, stream, qkv, VT, out);
}

// Round 8
// 165.844 us; speedup vs baseline: 1.5789x; 1.0610x over previous
//
#include <hip/hip_runtime.h>
#include <hip/hip_bf16.h>

#define D_MODEL 1024
#define N3      3072
#define TSEQ    2048
#define M_TOT   8192

typedef __bf16 bf16_8 __attribute__((ext_vector_type(8)));
typedef float  f32x4  __attribute__((ext_vector_type(4)));
typedef short  s16x4  __attribute__((ext_vector_type(4)));

static __device__ __forceinline__ unsigned short f2bf(float f) {
  __hip_bfloat16 h = __float2bfloat16(f);
  unsigned short u;
  __builtin_memcpy(&u, &h, 2);
  return u;
}
static __device__ __forceinline__ unsigned pack2(float lo, float hi) {
  return (unsigned)f2bf(lo) | ((unsigned)f2bf(hi) << 16);
}
static __device__ __forceinline__ void gload16(const void* g, void* l) {
  __builtin_amdgcn_global_load_lds((const __attribute__((address_space(1))) void*)g,
                                   (__attribute__((address_space(3))) void*)l, 16, 0, 0);
}

// ---------------- convert x: fp32 -> bf16 ----------------
__global__ void cvt_x_kernel(const float* __restrict__ x, __bf16* __restrict__ xb) {
  size_t i = (size_t)blockIdx.x * 256 + threadIdx.x;   // each thread: 4 floats
  float4 v = *(const float4*)(x + i * 4);
  ushort4 o;
  o.x = f2bf(v.x); o.y = f2bf(v.y); o.z = f2bf(v.z); o.w = f2bf(v.w);
  *(ushort4*)((unsigned short*)xb + i * 4) = o;
}

// ------------- convert+transpose W: [1024][3072] f32 -> WT [3072][1024] bf16 -------------
__global__ void cvt_w_kernel(const float* __restrict__ W, __bf16* __restrict__ WT) {
  __shared__ unsigned short tl[64][68];
  int t = threadIdx.x;
  int n0 = blockIdx.x * 64, k0 = blockIdx.y * 64;
  int rr = t >> 4, cc = (t & 15) * 4;
#pragma unroll
  for (int i = 0; i < 4; ++i) {
    int r = rr + i * 16;                       // k-local
    float4 v = *(const float4*)(W + (size_t)(k0 + r) * N3 + n0 + cc);
    tl[r][cc] = f2bf(v.x); tl[r][cc + 1] = f2bf(v.y);
    tl[r][cc + 2] = f2bf(v.z); tl[r][cc + 3] = f2bf(v.w);
  }
  __syncthreads();
#pragma unroll
  for (int i = 0; i < 4; ++i) {
    int rc = rr + i * 16;                      // n-local
    ushort4 o;
    o.x = tl[cc + 0][rc]; o.y = tl[cc + 1][rc];
    o.z = tl[cc + 2][rc]; o.w = tl[cc + 3][rc];
    *(ushort4*)((unsigned short*)WT + (size_t)(n0 + rc) * D_MODEL + k0 + cc) = o;
  }
}

// ------------- transpose V-part of qkv -> VT [bh][c=64][t=2048] bf16 -------------
__global__ void vtrans_kernel(const __bf16* __restrict__ qkv, __bf16* __restrict__ VT) {
  __shared__ unsigned short tl[64][68];
  int t = threadIdx.x;
  int t0 = blockIdx.x * 64;
  int bh = blockIdx.y;
  int b = bh >> 4, h = bh & 15;
  int rr = t >> 4, cc = (t & 15) * 4;
  const unsigned short* q16 = (const unsigned short*)qkv;
#pragma unroll
  for (int i = 0; i < 4; ++i) {
    int r = rr + i * 16;                       // t-local
    ushort4 v = *(const ushort4*)(q16 + (size_t)(b * TSEQ + t0 + r) * N3 + 2048 + h * 64 + cc);
    tl[r][cc] = v.x; tl[r][cc + 1] = v.y; tl[r][cc + 2] = v.z; tl[r][cc + 3] = v.w;
  }
  __syncthreads();
#pragma unroll
  for (int i = 0; i < 4; ++i) {
    int rc = rr + i * 16;                      // c-local
    ushort4 o;
    o.x = tl[cc + 0][rc]; o.y = tl[cc + 1][rc];
    o.z = tl[cc + 2][rc]; o.w = tl[cc + 3][rc];
    *(ushort4*)((unsigned short*)VT + (size_t)(bh * 64 + rc) * TSEQ + t0 + cc) = o;
  }
}

// ------------- GEMM: qkv = xb[8192][1024] @ WT[3072][1024]^T + bias, bf16 out -------------
// (R5 structure — measured best so far; R7's counted-vmcnt variant regressed.)
__global__ __launch_bounds__(256, 2) void gemm_qkv_kernel(
    const __bf16* __restrict__ A, const __bf16* __restrict__ Bt,
    const float* __restrict__ bias, __bf16* __restrict__ C) {
  __shared__ __align__(16) __bf16 Al[2][4096];
  __shared__ __align__(16) __bf16 Bl[2][4096];
  int tid = threadIdx.x;
  int wave = tid >> 6, lane = tid & 63;
  int lr = lane & 15, lg = lane >> 4;
  int m0 = blockIdx.x * 128, n0 = blockIdx.y * 128;
  int wm = (wave >> 1) * 64, wn = (wave & 1) * 64;

  const f32x4 fz = {0.f, 0.f, 0.f, 0.f};
  f32x4 acc[4][4];
#pragma unroll
  for (int i = 0; i < 4; ++i)
#pragma unroll
    for (int j = 0; j < 4; ++j) acc[i][j] = fz;

  auto stage = [&](int buf, int kt) {
#pragma unroll
    for (int call = 0; call < 2; ++call) {
      int cb = call * 256 + wave * 64;         // wave-uniform LDS chunk base
      int c = cb + lane;
      int row = c >> 2;
      int cir = (c & 3) ^ ((row >> 1) & 3);    // XOR swizzle (source side)
      gload16(A + (size_t)(m0 + row) * D_MODEL + kt * 32 + cir * 8, &Al[buf][cb * 8]);
      gload16(Bt + (size_t)(n0 + row) * D_MODEL + kt * 32 + cir * 8, &Bl[buf][cb * 8]);
    }
  };

  stage(0, 0);
  __syncthreads();
  for (int kt = 0; kt < 32; ++kt) {
    int buf = kt & 1;
    if (kt + 1 < 32) stage(buf ^ 1, kt + 1);
    bf16_8 af[4], bv[4];
#pragma unroll
    for (int mb = 0; mb < 4; ++mb) {
      int row = wm + mb * 16 + lr;
      int cir = lg ^ ((row >> 1) & 3);         // XOR swizzle (read side)
      af[mb] = *(const bf16_8*)&Al[buf][row * 32 + cir * 8];
    }
#pragma unroll
    for (int nb = 0; nb < 4; ++nb) {
      int row = wn + nb * 16 + lr;
      int cir = lg ^ ((row >> 1) & 3);
      bv[nb] = *(const bf16_8*)&Bl[buf][row * 32 + cir * 8];
    }
#pragma unroll
    for (int mb = 0; mb < 4; ++mb)
#pragma unroll
      for (int nb = 0; nb < 4; ++nb)
        acc[mb][nb] = __builtin_amdgcn_mfma_f32_16x16x32_bf16(af[mb], bv[nb], acc[mb][nb], 0, 0, 0);
    __syncthreads();
  }

  float bvs[4];
#pragma unroll
  for (int nb = 0; nb < 4; ++nb) bvs[nb] = bias[n0 + wn + nb * 16 + lr];
  unsigned short* C16 = (unsigned short*)C;
#pragma unroll
  for (int mb = 0; mb < 4; ++mb)
#pragma unroll
    for (int nb = 0; nb < 4; ++nb)
#pragma unroll
      for (int r = 0; r < 4; ++r) {
        int row = m0 + wm + mb * 16 + lg * 4 + r;
        int col = n0 + wn + nb * 16 + lr;
        C16[(size_t)row * N3 + col] = f2bf(acc[mb][nb][r] + bvs[nb]);
      }
}

// ------------- fused causal attention (flash-style, swapped QK^T) -------------
// q-tile = 64 rows (16/wave); grid (16,64)=1024 blocks, 4/CU; paired qt=(31-bx),(bx)
// => 33 kv-tile units per block. LDS exactly 32KB; epilogue stores direct to global.
__global__ __launch_bounds__(256, 4) void attn_kernel(
    const __bf16* __restrict__ qkv, const __bf16* __restrict__ VT,
    float* __restrict__ out) {
  __shared__ __align__(16) char smem[32768];
  __bf16* Kl = (__bf16*)smem;                  // [2][4096]
  __bf16* Vl = (__bf16*)(smem + 16384);        // [2][4096]

  int bx = blockIdx.x, bh = blockIdx.y;        // grid (16, 64)
  int b = bh >> 4, h = bh & 15;
  int tid = threadIdx.x, wave = tid >> 6, lane = tid & 63;
  int lr = lane & 15, lg = lane >> 4;

  const __bf16* Kg = qkv + (size_t)b * TSEQ * N3 + 1024 + h * 64;  // + t*N3
  const __bf16* Vg = VT + (size_t)bh * 64 * TSEQ;                  // + c*TSEQ
  const float SC = 0.04508422f;                // log2(e)/32  (scale 1/sqrt(1024))

  auto stage = [&](int buf, int kv0) {
#pragma unroll
    for (int call = 0; call < 2; ++call) {
      int cb = call * 256 + wave * 64;
      int c = cb + lane;
      int row = c >> 3;
      int cir = (c & 7) ^ (row & 7);           // XOR swizzle (source side); row stride 128B
      gload16(Kg + (size_t)(kv0 + row) * N3 + cir * 8, Kl + buf * 4096 + cb * 8);
      gload16(Vg + (size_t)row * TSEQ + kv0 + cir * 8, Vl + buf * 4096 + cb * 8);
    }
  };

  for (int pass = 0; pass < 2; ++pass) {
    int qt = pass ? bx : (31 - bx);
    int q0 = qt * 64 + wave * 16;              // wave's 16 q-rows

    // Q as B-fragment: B[k=c][n=q] = Q[q][c]
    bf16_8 qf[2];
#pragma unroll
    for (int kk = 0; kk < 2; ++kk)
      qf[kk] = *(const bf16_8*)&qkv[(size_t)(b * TSEQ + q0 + lr) * N3 + h * 64 + kk * 32 + lg * 8];

    float mreg = -1e30f, lreg = 0.f;
    const f32x4 fz = {0.f, 0.f, 0.f, 0.f};
    f32x4 oacc[4];
#pragma unroll
    for (int i = 0; i < 4; ++i) oacc[i] = fz;

    int ntiles = qt + 1;
    stage(0, 0);
    __syncthreads();
    for (int tt = 0; tt < ntiles; ++tt) {
      int buf = tt & 1;
      int kv0 = tt * 64;
      if (tt + 1 < ntiles) stage(buf ^ 1, (tt + 1) * 64);
      if (kv0 <= q0 + 15) {
        const __bf16* Kb = Kl + buf * 4096;
        const __bf16* Vb = Vl + buf * 4096;
        // S^T[kv][q] = K · Q^T
        f32x4 st[4];
#pragma unroll
        for (int i = 0; i < 4; ++i) st[i] = fz;
#pragma unroll
        for (int kk = 0; kk < 2; ++kk) {
          bf16_8 kf[4];
#pragma unroll
          for (int mb = 0; mb < 4; ++mb) {
            int row = mb * 16 + lr;
            int cir = (kk * 4 + lg) ^ (row & 7); // XOR swizzle (read side)
            kf[mb] = *(const bf16_8*)&Kb[row * 64 + cir * 8];
          }
          __builtin_amdgcn_s_setprio(1);
#pragma unroll
          for (int mb = 0; mb < 4; ++mb)
            st[mb] = __builtin_amdgcn_mfma_f32_16x16x32_bf16(kf[mb], qf[kk], st[mb], 0, 0, 0);
          __builtin_amdgcn_s_setprio(0);
        }
        // mask + scale into log2 domain (uniform branch)
        float sv[4][4];
        if (kv0 + 63 > q0) {
#pragma unroll
          for (int mb = 0; mb < 4; ++mb)
#pragma unroll
            for (int r = 0; r < 4; ++r) {
              float s = st[mb][r] * SC;
              int kv = kv0 + mb * 16 + lg * 4 + r;
              sv[mb][r] = (kv > q0 + lr) ? -1e30f : s;
            }
        } else {
#pragma unroll
          for (int mb = 0; mb < 4; ++mb)
#pragma unroll
            for (int r = 0; r < 4; ++r)
              sv[mb][r] = st[mb][r] * SC;
        }
        // online softmax (per q-column state; column = lr), defer-max THR=8
        float a0 = fmaxf(fmaxf(sv[0][0], sv[0][1]), fmaxf(sv[0][2], sv[0][3]));
        float a1 = fmaxf(fmaxf(sv[1][0], sv[1][1]), fmaxf(sv[1][2], sv[1][3]));
        float a2 = fmaxf(fmaxf(sv[2][0], sv[2][1]), fmaxf(sv[2][2], sv[2][3]));
        float a3 = fmaxf(fmaxf(sv[3][0], sv[3][1]), fmaxf(sv[3][2], sv[3][3]));
        float tmx = fmaxf(fmaxf(a0, a1), fmaxf(a2, a3));
        tmx = fmaxf(tmx, __shfl_xor(tmx, 16, 64));
        tmx = fmaxf(tmx, __shfl_xor(tmx, 32, 64));
        if (!__all(tmx <= mreg + 8.f)) {
          float mn = fmaxf(mreg, tmx);
          float fac = __builtin_amdgcn_exp2f(mreg - mn);
          mreg = mn;
          lreg *= fac;
#pragma unroll
          for (int mbc = 0; mbc < 4; ++mbc) oacc[mbc] *= fac;
        }
        float ps = 0.f;
        unsigned pw[4][2];
#pragma unroll
        for (int mb = 0; mb < 4; ++mb) {
          float p0 = __builtin_amdgcn_exp2f(sv[mb][0] - mreg);
          float p1 = __builtin_amdgcn_exp2f(sv[mb][1] - mreg);
          float p2 = __builtin_amdgcn_exp2f(sv[mb][2] - mreg);
          float p3 = __builtin_amdgcn_exp2f(sv[mb][3] - mreg);
          ps += (p0 + p1) + (p2 + p3);
          pw[mb][0] = pack2(p0, p1);
          pw[mb][1] = pack2(p2, p3);
        }
        ps += __shfl_xor(ps, 16, 64);
        ps += __shfl_xor(ps, 32, 64);
        lreg += ps;
        // PV: O^T[c][q] += V^T · P^T  (16x16x16; pw pairs are the B-fragment directly)
#pragma unroll
        for (int mb = 0; mb < 4; ++mb) {
          s16x4 vf[4];
          int chunk = mb * 2 + (lg >> 1);      // 16B chunk of k-range mb*16 + lg*4
#pragma unroll
          for (int mbc = 0; mbc < 4; ++mbc) {
            int row = mbc * 16 + lr;
            int cir = chunk ^ (row & 7);       // same 16B-granule swizzle involution
            vf[mbc] = *(const s16x4*)((const char*)Vb + row * 128 + cir * 16 + (lg & 1) * 8);
          }
          union { unsigned u[2]; s16x4 v; } pf;
          pf.u[0] = pw[mb][0];
          pf.u[1] = pw[mb][1];
          __builtin_amdgcn_s_setprio(1);
#pragma unroll
          for (int mbc = 0; mbc < 4; ++mbc)
            oacc[mbc] = __builtin_amdgcn_mfma_f32_16x16x16bf16_1k(vf[mbc], pf.v, oacc[mbc], 0, 0, 0);
          __builtin_amdgcn_s_setprio(0);
        }
      }
      __syncthreads();
    }

    // epilogue: direct f32x4 global stores (row's 256B fully covered by the wave)
    float invl = 1.f / lreg;
    float* dst = out + (size_t)(b * TSEQ + q0 + lr) * D_MODEL + h * 64 + lg * 4;
#pragma unroll
    for (int mbc = 0; mbc < 4; ++mbc) {
      float4 v;
      v.x = oacc[mbc][0] * invl; v.y = oacc[mbc][1] * invl;
      v.z = oacc[mbc][2] * invl; v.w = oacc[mbc][3] * invl;
      *(float4*)(dst + mbc * 16) = v;
    }
  }
}

extern "C" void kernel_launch(void* const* d_in, const int* in_sizes, int n_in,
                              void* d_out, int out_size, void* d_ws, size_t ws_size,
                              hipStream_t stream) {
  const float* x = (const float*)d_in[0];
  const float* W = (const float*)d_in[1];
  const float* bias = (const float*)d_in[2];
  float* out = (float*)d_out;
  char* ws = (char*)d_ws;
  __bf16* xb  = (__bf16*)(ws);                        // 16,777,216 B
  __bf16* WT  = (__bf16*)(ws + (size_t)16777216);     //  6,291,456 B
  __bf16* qkv = (__bf16*)(ws + (size_t)23068672);     // 50,331,648 B
  __bf16* VT  = (__bf16*)(ws + (size_t)73400320);     // 16,777,216 B  (total ~90 MB)

  hipLaunchKernelGGL(cvt_x_kernel, dim3(8192), dim3(256), 0, stream, x, xb);
  hipLaunchKernelGGL(cvt_w_kernel, dim3(48, 16), dim3(256), 0, stream, W, WT);
  hipLaunchKernelGGL(gemm_qkv_kernel, dim3(64, 24), dim3(256), 0, stream, xb, WT, bias, qkv);
  hipLaunchKernelGGL(vtrans_kernel, dim3(32, 64), dim3(256), 0, stream, qkv, VT);
  hipLaunchKernelGGL(attn_kernel, dim3(16, 64), dim3(256), 0, stream, qkv, VT, out);
}